// Round 4
// baseline (392.615 us; speedup 1.0000x reference)
//
#include <hip/hip_runtime.h>
#include <stdint.h>
#include <math.h>

// Native 16-byte vector type — __builtin_nontemporal_{load,store} requires a
// native vector, not HIP's float4 class.
typedef float vf4 __attribute__((ext_vector_type(4)));

#define BS 256u      // block size (compile-time so offsets fold to immediates)
#define UNROLL 8u    // independent 16-B loads in flight per thread

// Order-preserving float -> uint32 encoding: f1 < f2  <=>  enc(f1) < enc(f2)
__device__ __forceinline__ uint32_t enc_f32(float f) {
    uint32_t b = __float_as_uint(f);
    return (b & 0x80000000u) ? ~b : (b | 0x80000000u);
}
__device__ __forceinline__ float dec_f32(uint32_t u) {
    uint32_t b = (u & 0x80000000u) ? (u ^ 0x80000000u) : ~u;
    return __uint_as_float(b);
}

__global__ void init_ws_kernel(uint32_t* ws) {
    ws[0] = 0xFFFFFFFFu;  // +inf encoded (running min slot)
    ws[1] = 0x00000000u;  // -inf encoded (running max slot)
}

__device__ __forceinline__ void mm4(vf4 v, float& mn, float& mx) {
    mn = fminf(mn, fminf(fminf(v.x, v.y), fminf(v.z, v.w)));
    mx = fmaxf(mx, fmaxf(fmaxf(v.x, v.y), fmaxf(v.z, v.w)));
}

// 8x-unrolled min/max reduction: 8 independent 16B loads in flight per thread
// per iteration (128 B). Independent accumulators keep dest registers disjoint
// so the compiler interleaves waitcnt (vmcnt(7)..vmcnt(0)) with consumption.
__global__ __launch_bounds__(BS) void minmax_kernel(
    const vf4* __restrict__ x4, unsigned n4,
    uint32_t* __restrict__ ws)
{
    float mn_[UNROLL], mx_[UNROLL];
    #pragma unroll
    for (unsigned u = 0; u < UNROLL; ++u) { mn_[u] = INFINITY; mx_[u] = -INFINITY; }

    const unsigned stride = gridDim.x * BS * UNROLL;   // vf4 elements per iter
    unsigned base = blockIdx.x * BS * UNROLL + threadIdx.x;

    for (; base + (UNROLL - 1u) * BS < n4; base += stride) {
        vf4 v[UNROLL];
        #pragma unroll
        for (unsigned u = 0; u < UNROLL; ++u) v[u] = x4[base + u * BS];
        #pragma unroll
        for (unsigned u = 0; u < UNROLL; ++u) mm4(v[u], mn_[u], mx_[u]);
    }
    for (; base < n4; base += BS) {
        mm4(x4[base], mn_[0], mx_[0]);
    }

    float mn = mn_[0], mx = mx_[0];
    #pragma unroll
    for (unsigned u = 1; u < UNROLL; ++u) {
        mn = fminf(mn, mn_[u]);
        mx = fmaxf(mx, mx_[u]);
    }

    #pragma unroll
    for (int off = 32; off > 0; off >>= 1) {
        mn = fminf(mn, __shfl_down(mn, off, 64));
        mx = fmaxf(mx, __shfl_down(mx, off, 64));
    }
    __shared__ float smn[4], smx[4];
    const int wave = threadIdx.x >> 6;
    const int lane = threadIdx.x & 63;
    if (lane == 0) { smn[wave] = mn; smx[wave] = mx; }
    __syncthreads();
    if (threadIdx.x == 0) {
        mn = fminf(fminf(smn[0], smn[1]), fminf(smn[2], smn[3]));
        mx = fmaxf(fmaxf(smx[0], smx[1]), fmaxf(smx[2], smx[3]));
        atomicMin(&ws[0], enc_f32(mn));
        atomicMax(&ws[1], enc_f32(mx));
    }
}

__device__ __forceinline__ vf4 q4(vf4 v, float mn, float scale, float inv_scale) {
    vf4 r;
    r.x = rintf((v.x - mn) * scale) * inv_scale + mn;
    r.y = rintf((v.y - mn) * scale) * inv_scale + mn;
    r.z = rintf((v.z - mn) * scale) * inv_scale + mn;
    r.w = rintf((v.w - mn) * scale) * inv_scale + mn;
    return r;
}

__global__ __launch_bounds__(BS) void quant_kernel(
    const vf4* __restrict__ x4, unsigned n4,
    vf4* __restrict__ o4,
    const uint32_t* __restrict__ ws)
{
    const float mn = dec_f32(ws[0]);
    const float mx = dec_f32(ws[1]);
    const float scale = 255.0f / (mx - mn);
    const float inv_scale = 1.0f / scale;

    const unsigned stride = gridDim.x * BS * UNROLL;
    unsigned base = blockIdx.x * BS * UNROLL + threadIdx.x;

    for (; base + (UNROLL - 1u) * BS < n4; base += stride) {
        vf4 v[UNROLL];
        #pragma unroll
        for (unsigned u = 0; u < UNROLL; ++u) v[u] = x4[base + u * BS];
        // Output is written once and never re-read: stream past the caches so
        // the input (hot in L3 for the next iteration's pass 1) isn't evicted.
        #pragma unroll
        for (unsigned u = 0; u < UNROLL; ++u)
            __builtin_nontemporal_store(q4(v[u], mn, scale, inv_scale), &o4[base + u * BS]);
    }
    for (; base < n4; base += BS) {
        __builtin_nontemporal_store(q4(x4[base], mn, scale, inv_scale), &o4[base]);
    }
}

// Scalar-remainder cleanup (n % 4 != 0) — not hit for this problem's shape
// (51,380,224 % 4 == 0) but kept for generality.
__global__ void quant_tail_kernel(const float* __restrict__ x, long start, long n,
                                  float* __restrict__ o,
                                  const uint32_t* __restrict__ ws)
{
    const float mn = dec_f32(ws[0]);
    const float mx = dec_f32(ws[1]);
    const float scale = 255.0f / (mx - mn);
    const float inv_scale = 1.0f / scale;
    long i = start + threadIdx.x;
    if (i < n) o[i] = rintf((x[i] - mn) * scale) * inv_scale + mn;
}

__global__ void minmax_tail_kernel(const float* __restrict__ x, long start, long n,
                                   uint32_t* __restrict__ ws)
{
    long i = start + threadIdx.x;
    if (i < n) {
        float v = x[i];
        atomicMin(&ws[0], enc_f32(v));
        atomicMax(&ws[1], enc_f32(v));
    }
}

extern "C" void kernel_launch(void* const* d_in, const int* in_sizes, int n_in,
                              void* d_out, int out_size, void* d_ws, size_t ws_size,
                              hipStream_t stream) {
    const float* x = (const float*)d_in[0];
    float* out = (float*)d_out;
    const long n = (long)in_sizes[0];
    const unsigned n4 = (unsigned)(n / 4);
    uint32_t* ws = (uint32_t*)d_ws;

    init_ws_kernel<<<1, 1, 0, stream>>>(ws);

    // 2048 blocks x 256 threads = exactly 8 blocks/CU x 256 CUs co-resident
    // (32 waves/CU, max occupancy). Each thread: ~3 iterations of 128 B.
    const int grid = 2048;

    minmax_kernel<<<grid, BS, 0, stream>>>((const vf4*)x, n4, ws);
    if (n % 4) minmax_tail_kernel<<<1, 256, 0, stream>>>(x, (long)n4 * 4, n, ws);

    quant_kernel<<<grid, BS, 0, stream>>>((const vf4*)x, n4, (vf4*)out, ws);
    if (n % 4) quant_tail_kernel<<<1, 256, 0, stream>>>(x, (long)n4 * 4, n, out, ws);
}